// Round 10
// baseline (262.337 us; speedup 1.0000x reference)
//
#include <hip/hip_runtime.h>

// CausalSelfAttention: x[4,2048,1024] fp32 -> out fp32
// Pipeline (all bf16 MFMA, fp32 accum):
//  1) cvt x -> bf16            2) transpose+cvt W_attn & W_proj -> bf16 [N][K]
//  3) gemm_qkv (128x384 tile, BK=32, 2-phase counted-vmcnt, 512 blocks =
//     EXACTLY 2 uniform rounds on 256 CUs) -> Q (pre-scaled 0.125*log2e),
//     K, V TRANSPOSED [b,h,d,s] (scatter)
//  4) flash attention: 64-row strips paired (s,31-s) -> 33 tiles/block,
//     1024 uniform blocks (R9, kept)
//  5) gemm_proj (128x64 tile, 1024 blocks, 3/CU) + bias -> out fp32
//
// R10 post-mortem of R9 (248.2us; gemm8p 86.8us REGRESSED from R4's 79):
//   4-wave/256-thr retile lost per-block efficiency; 768 blocks at ~1/CU
//   residency = 3 sequential rounds. History: R3 79.8, R4 79.0, R9 86.8 ->
//   the binder is MAKESPAN GRANULARITY: 384 big blocks = 2 rounds w/ half
//   the chip idle in round 2.
//   FIX: 128x384 tiles -> 64x8 = 512 blocks = exactly 2 full uniform rounds.
//   Block area 0.75x of 256^2 -> makespan 1.5xT vs 2xT -> ~60us predicted.
//   8 waves 1Mx8N (wave 128x48, acc[8][3]=96 regs, lighter than R4's 128);
//   LDS A 2x8KB + B 2x24KB = 64KB exactly; 4 x 8KB issues/K-tile;
//   bx = lin&7 -> each XCD's 768KB B-panel L2-resident; A panel shared by
//   all 8 XCDs concurrently (L3 serves).
// Schedule per K-tile (counted vmcnt, never 0 in loop; same invariant as R4):
//   P0 {RD_A x8, RD_B 0-1, issue B0/B1(t+1), BAR, setprio1, 16 MFMA,
//       setprio0, BAR}
//   P1 {RD_B 2, issue B2(t+1) + A(t+2), vmcnt(1), BAR, setprio1, 8 MFMA,
//       setprio0, BAR}
//   outstanding: 1 -> P0 +2 -> P1 +2 = 5 -> vmcnt(1) drains 4 (t+1 complete,
//   A(t+2) in flight). Overwrite safety: B(t+1) -> other-parity buf (reads
//   done at t-1); A(t+2) -> current A buf (reads done in P0, barrier-ordered).
//   Tail issues clamped (identical-data reload, benign).
// Epilogue: 384-wide tile straddles Q/K/V -> which-split PER 16-col FRAG
//   (wave-uniform: frag base 16-aligned, 16 | 1024).
// Rotation swizzle (conflict-free, verified R3/R4/R9): writer thread t loads
//   global chunk ((t&3)-((t>>3)&3))&3 into slot t&3 of row t>>2(+rowoff);
//   reader slot (quad+(l15>>1))&3. Valid for any 16-aligned frag base.
// MFMA 16x16x32 bf16 layouts (HW-verified per guide):
//   A: a[j] = A[m=lane&15][k=quad*8+j]  (quad=lane>>4)
//   B: b[j] = B[k=quad*8+j][n=lane&15]  (from Bt[n][k] read at row n)
//   C/D: c[i] = D[row=quad*4+i][col=lane&15]
// R5 lesson: launch_bounds caps regs (cap=512/w for 512-thr blocks); (512,2)
//   -> cap 256 >= ~160 working set, no spill.

#define BATCH 4
#define SEQ   2048
#define EMB   1024
#define NH    16
#define HD    64

typedef __bf16 bf16;
typedef __bf16 bf16x8 __attribute__((ext_vector_type(8)));
typedef float  f32x4  __attribute__((ext_vector_type(4)));

// direct global->LDS 16B copy: LDS dest is wave-uniform base + lane*16
__device__ __forceinline__ void ld_lds16(const void* g, void* l) {
  __builtin_amdgcn_global_load_lds(
      (const __attribute__((address_space(1))) void*)g,
      (__attribute__((address_space(3))) void*)l, 16, 0, 0);
}

// ---------------- convert fp32 -> bf16 ----------------
__global__ void cvt_f32_bf16(const float* __restrict__ in, bf16* __restrict__ out, int n) {
  int i = (blockIdx.x * blockDim.x + threadIdx.x) * 4;
  if (i + 3 < n) {
    float4 v = *(const float4*)(in + i);
    bf16 o0 = (bf16)v.x, o1 = (bf16)v.y, o2 = (bf16)v.z, o3 = (bf16)v.w;
    out[i] = o0; out[i+1] = o1; out[i+2] = o2; out[i+3] = o3;
  }
}

// ---------------- transpose + convert both weights (one launch) ----------------
__global__ void transpose_cvt2(const float* __restrict__ Wa, const float* __restrict__ Wp,
                               bf16* __restrict__ WaT, bf16* __restrict__ WpT) {
  __shared__ float tile[32][33];
  int bx = blockIdx.x;
  const float* W; bf16* WT; int N;
  if (bx < 96) { W = Wa; WT = WaT; N = 3072; }
  else         { W = Wp; WT = WpT; N = 1024; bx -= 96; }
  int n0 = bx * 32, k0 = blockIdx.y * 32;
  int tx = threadIdx.x & 31, ty = threadIdx.x >> 5;
#pragma unroll
  for (int r = 0; r < 4; r++) {
    int k = k0 + ty + r * 8;
    tile[ty + r * 8][tx] = W[(long)k * N + n0 + tx];
  }
  __syncthreads();
#pragma unroll
  for (int r = 0; r < 4; r++) {
    int n = n0 + ty + r * 8;
    WT[(long)n * EMB + k0 + tx] = (bf16)tile[tx][ty + r * 8];
  }
}

#define QSCALE 0.18033688f   // (1/8) * log2(e)

// ---------------- 128x384 phase-pipelined QKV GEMM ----------------
// A[8192][1024] bf16 x Bt[3072][1024] bf16 + bias -> Q/K/V.
// Grid 512 (= 2x256 exact) x 512 thr (8 waves, 1Mx8N; wave = 128x48).
__global__ __launch_bounds__(512, 2) void gemm_qkv(
    const bf16* __restrict__ A, const bf16* __restrict__ Bt,
    const float* __restrict__ bias,
    bf16* __restrict__ q, bf16* __restrict__ k, bf16* __restrict__ v)
{
  __shared__ __align__(16) bf16 lds[32768];   // A[2][4096] | B[2][12288] = 64KB
  int lin = blockIdx.x;
  int bx = lin & 7;                  // col-panel == XCD (B-panel L2-resident)
  int by = lin >> 3;                 // 64 row-panels
  int m0 = by * 128, n0 = bx * 384;
  int t = threadIdx.x;
  int wid = t >> 6, lane = t & 63;
  int l15 = lane & 15, quad = lane >> 4;
  int wc = wid;                      // wave: all 128 rows x cols wc*48..+47

  const bf16* Ag = A + (long)m0 * EMB;
  const bf16* Bg = Bt + (long)n0 * EMB;

  f32x4 acc[8][3] = {};
  bf16x8 af[8], bfr[3];
  constexpr int NT = EMB / 32;       // 32 K-tiles
  // physical chunk slot for all frag reads (rotation swizzle; see header)
  int ph8 = ((quad + (l15 >> 1)) & 3) * 8;

#define LDSA(b) (lds + (b) * 4096)
#define LDSB(b) (lds + 8192 + (b) * 12288)

  // stage a 128-row x 32-col panel: 1 gload_lds per thread (8KB, 512 thr).
  // writer: thread t loads global chunk ((t&3)-((t>>3)&3))&3 into slot t&3
  // of row rowoff + (t>>2); wave wid covers rows rowoff+wid*16..+15.
#define ISSUE128(gbase, rowoff, ldst, ktt)                                     \
  { int r_ = (rowoff) + (t >> 2);                                              \
    int g_ = ((t & 3) - ((t >> 3) & 3)) & 3;                                   \
    ld_lds16(&(gbase)[(long)r_ * EMB + (ktt) + g_ * 8],                        \
             (ldst) + ((rowoff) + wid * 16) * 32); }

#define RD_A(mi) { int r_ = (mi) * 16 + l15;                                   \
    af[mi] = *(const bf16x8*)&Ab[r_ * 32 + ph8]; }
#define RD_B(ni) { int r_ = wc * 48 + (ni) * 16 + l15;                         \
    bfr[ni] = *(const bf16x8*)&Bb[r_ * 32 + ph8]; }

#define FENCE asm volatile("" ::: "memory")
#define BAR   { FENCE; __builtin_amdgcn_s_barrier(); FENCE; }

#define MFMAC2(n0_, n1_)                                                       \
  { __builtin_amdgcn_s_setprio(1);                                             \
    _Pragma("unroll") for (int mi_ = 0; mi_ < 8; ++mi_) {                      \
      acc[mi_][n0_] = __builtin_amdgcn_mfma_f32_16x16x32_bf16(                 \
          af[mi_], bfr[n0_], acc[mi_][n0_], 0, 0, 0);                          \
      acc[mi_][n1_] = __builtin_amdgcn_mfma_f32_16x16x32_bf16(                 \
          af[mi_], bfr[n1_], acc[mi_][n1_], 0, 0, 0);                          \
    }                                                                          \
    __builtin_amdgcn_s_setprio(0); }

#define MFMAC1(n0_)                                                            \
  { __builtin_amdgcn_s_setprio(1);                                             \
    _Pragma("unroll") for (int mi_ = 0; mi_ < 8; ++mi_)                        \
      acc[mi_][n0_] = __builtin_amdgcn_mfma_f32_16x16x32_bf16(                 \
          af[mi_], bfr[n0_], acc[mi_][n0_], 0, 0, 0);                          \
    __builtin_amdgcn_s_setprio(0); }

  // prologue: tile0 complete (4 issues) + A(tile1) in flight
  ISSUE128(Ag, 0,   LDSA(0), 0);
  ISSUE128(Bg, 0,   LDSB(0), 0);
  ISSUE128(Bg, 128, LDSB(0), 0);
  ISSUE128(Bg, 256, LDSB(0), 0);
  ISSUE128(Ag, 0,   LDSA(1), 32);
  asm volatile("s_waitcnt vmcnt(1)" ::: "memory");
  BAR;

#pragma unroll 2
  for (int tt = 0; tt < NT; ++tt) {
    const bf16* Ab = LDSA(tt & 1);
    const bf16* Bb = LDSB(tt & 1);
    bf16* Bn = LDSB((tt + 1) & 1);
    bf16* Ac = LDSA(tt & 1);                         // A(t+2): (tt+2)&1==tt&1
    int kn  = (tt + 1 < NT ? tt + 1 : NT - 1) * 32;  // clamped at tail:
    int kn2 = (tt + 2 < NT ? tt + 2 : NT - 1) * 32;  // dummy identical reload

    // P0: all A frags + B frags 0-1; prefetch B0/B1(t+1)
#pragma unroll
    for (int mi = 0; mi < 8; ++mi) RD_A(mi);
    RD_B(0); RD_B(1);
    ISSUE128(Bg, 0,   Bn, kn);
    ISSUE128(Bg, 128, Bn, kn);
    BAR; MFMAC2(0, 1); BAR;
    // P1: B frag 2; prefetch B2(t+1) + A(t+2) (A reads done in P0)
    RD_B(2);
    ISSUE128(Bg, 256, Bn, kn);
    ISSUE128(Ag, 0,   Ac, kn2);
    asm volatile("s_waitcnt vmcnt(1)" ::: "memory");  // t+1 fully landed
    BAR; MFMAC1(2); BAR;
  }

  asm volatile("s_waitcnt vmcnt(0)" ::: "memory");   // drain clamped DMAs
  __syncthreads();

  // ---------------- epilogue: which-split PER 16-col FRAG ----------------
#pragma unroll
  for (int mi = 0; mi < 8; ++mi)
#pragma unroll
    for (int ni = 0; ni < 3; ++ni) {
      int gcol = n0 + wc * 48 + ni * 16 + l15;
      float bv = bias[gcol];
      int which = gcol >> 10;        // wave-uniform (frag base 16-aligned)
      int e = gcol & 1023, h = e >> 6, d = e & 63;
      if (which < 2) {
        bf16* dst = (which == 0) ? q : k;
        float scale = (which == 0) ? QSCALE : 1.0f;
#pragma unroll
        for (int i = 0; i < 4; ++i) {
          int grow = m0 + mi * 16 + quad * 4 + i;
          int b = grow >> 11, ss = grow & 2047;
          dst[(((long)b * NH + h) * SEQ + ss) * HD + d] =
              (bf16)((acc[mi][ni][i] + bv) * scale);
        }
      } else {
        // V^T scatter (proven: WRITE_SIZE stays ideal, L2 absorbs)
#pragma unroll
        for (int i = 0; i < 4; ++i) {
          int grow = m0 + mi * 16 + quad * 4 + i;
          int b = grow >> 11, ss = grow & 2047;
          v[(((long)b * NH + h) * HD + d) * SEQ + ss] =
              (bf16)(acc[mi][ni][i] + bv);
        }
      }
    }
#undef LDSA
#undef LDSB
#undef ISSUE128
#undef RD_A
#undef RD_B
#undef MFMAC2
#undef MFMAC1
}

// ---------------- proj GEMM (R0 known-good): 128x64 tile, 3 blocks/CU ------
__global__ __launch_bounds__(256, 3) void gemm_proj(
    const bf16* __restrict__ A, const bf16* __restrict__ Bt,
    const float* __restrict__ bias, float* __restrict__ out)
{
  __shared__ __align__(16) bf16 Al[128 * 64];
  __shared__ __align__(16) bf16 Bl[64 * 64];
  int lin = blockIdx.x;
  int xcd = lin & 7, s = lin >> 3;
  int bx = s >> 3, by = xcd * 8 + (s & 7);
  int m0 = by * 128;
  int n0 = bx * 64;
  int t = threadIdx.x;
  int wave = t >> 6, lane = t & 63;
  int l15 = lane & 15, quad = lane >> 4;
  int wm = (wave & 1) * 64, wn = (wave >> 1) * 32;

  f32x4 acc[4][2] = {};

  for (int kt = 0; kt < EMB; kt += 64) {
    __syncthreads();
#pragma unroll
    for (int it = 0; it < 4; ++it) {         // A: 128 rows x 8 units
      int c = it * 256 + t;
      int row = c >> 3, u = c & 7;
      ld_lds16(&A[(long)(m0 + row) * EMB + kt + ((u ^ (row & 7)) * 8)],
               &Al[(it * 256 + wave * 64) * 8]);
    }
    {
      int c = t;                              // B: 64 rows x 8 units
      int row = c >> 3, u = c & 7;
      ld_lds16(&Bt[(long)(n0 + row) * EMB + kt + ((u ^ (row & 7)) * 8)],
               &Bl[(wave * 64) * 8]);
      c = 256 + t;
      row = c >> 3; u = c & 7;
      ld_lds16(&Bt[(long)(n0 + row) * EMB + kt + ((u ^ (row & 7)) * 8)],
               &Bl[(256 + wave * 64) * 8]);
    }
    __syncthreads();
#pragma unroll
    for (int ks = 0; ks < 2; ++ks) {
      bf16x8 af[4], bfr[2];
#pragma unroll
      for (int i = 0; i < 4; ++i) {
        int r = wm + i * 16 + l15;
        af[i] = *(const bf16x8*)(&Al[r * 64 + (((ks * 4 + quad) ^ (r & 7)) * 8)]);
      }
#pragma unroll
      for (int i = 0; i < 2; ++i) {
        int r = wn + i * 16 + l15;
        bfr[i] = *(const bf16x8*)(&Bl[r * 64 + (((ks * 4 + quad) ^ (r & 7)) * 8)]);
      }
#pragma unroll
      for (int mi = 0; mi < 4; ++mi)
#pragma unroll
        for (int ni = 0; ni < 2; ++ni)
          acc[mi][ni] = __builtin_amdgcn_mfma_f32_16x16x32_bf16(af[mi], bfr[ni], acc[mi][ni], 0, 0, 0);
    }
  }

#pragma unroll
  for (int mi = 0; mi < 4; ++mi)
#pragma unroll
    for (int ni = 0; ni < 2; ++ni) {
      int gcol = n0 + wn + ni * 16 + l15;
      float bv = bias[gcol];
#pragma unroll
      for (int i = 0; i < 4; ++i) {
        int grow = m0 + wm + mi * 16 + quad * 4 + i;
        out[(long)grow * EMB + gcol] = acc[mi][ni][i] + bv;
      }
    }
}

// ---------------- flash attention (64-row strips, paired; 1024 uniform) ----
// Decode: xcd=L&7, a=L>>3; head = (L&7)+8*(a&7); pr = a>>3 in [0,16).
// Pass 0 runs strip 31-pr, pass 1 runs strip pr (strips of 64 q-rows).
// ntiles(strip s) = s+1 -> every block stages exactly 33 tiles. Grid 1024
// = 4 blocks/CU, all identical length -> sustained 16 waves/CU, no tail.
#define LDP 72   // P row stride (elems): conflict-free, 16B-aligned

__global__ __launch_bounds__(256, 4) void attn(
    const bf16* __restrict__ Q, const bf16* __restrict__ K,
    const bf16* __restrict__ Vt, bf16* __restrict__ Y)
{
  __shared__ __align__(16) bf16 Kl[64 * 64];        // 8 KB
  __shared__ __align__(16) bf16 Vl[64 * 64];        // 8 KB
  __shared__ __align__(16) bf16 Pl[4][16 * LDP];    // 9 KB, per-wave
  int L = blockIdx.x;
  int a = L >> 3;
  int hd = (L & 7) + 8 * (a & 7);
  int pr = a >> 3;
  int b = hd >> 4, h = hd & 15;
  const bf16* Qp  = Q  + (((long)b * NH + h) * SEQ) * HD;
  const bf16* Kp  = K  + (((long)b * NH + h) * SEQ) * HD;
  const bf16* Vtp = Vt + (((long)b * NH + h) * HD) * SEQ;
  int t = threadIdx.x, wave = t >> 6, lane = t & 63;
  int l15 = lane & 15, quad = lane >> 4;

#pragma unroll 1
  for (int pass = 0; pass < 2; ++pass) {
    int sp = (pass == 0) ? (31 - pr) : pr;    // strip index [0,32)
    int q0 = sp * 64;
    int wq0 = q0 + wave * 16;                 // wave's 16 q-rows

    // Q fragment: rows wq0..wq0+15, k split 0/32
    bf16x8 qf[2];
    {
      const bf16* qrow = Qp + (long)(wq0 + l15) * HD + quad * 8;
      qf[0] = *(const bf16x8*)(qrow);
      qf[1] = *(const bf16x8*)(qrow + 32);
    }
    float lrow[4] = {};
    f32x4 oacc[4] = {};

    int ntiles = sp + 1;          // keys 0..q0+63
#pragma unroll 1
    for (int kt = 0; kt < ntiles; ++kt) {
      int k0 = kt * 64;
      __syncthreads();
      // stage K [key][d], V^T [d][key]: unit row*8+u holds chunk u^(row&7)
#pragma unroll
      for (int it = 0; it < 2; ++it) {
        int cu = it * 256 + t;
        int row = cu >> 3, u = cu & 7;
        ld_lds16(&Kp[(long)(k0 + row) * HD + ((u ^ (row & 7)) * 8)],
                 &Kl[(it * 256 + wave * 64) * 8]);
        ld_lds16(&Vtp[(long)row * SEQ + k0 + ((u ^ (row & 7)) * 8)],
                 &Vl[(it * 256 + wave * 64) * 8]);
      }
      __syncthreads();

      // scores: S[16q x 64k]
      f32x4 sc[4] = {};
#pragma unroll
      for (int kk = 0; kk < 2; ++kk) {
#pragma unroll
        for (int ni = 0; ni < 4; ++ni) {
          int r = ni * 16 + l15, u = kk * 4 + quad;
          bf16x8 kfr = *(const bf16x8*)(&Kl[r * 64 + ((u ^ (r & 7)) * 8)]);
          sc[ni] = __builtin_amdgcn_mfma_f32_16x16x32_bf16(qf[kk], kfr, sc[ni], 0, 0, 0);
        }
      }

      bool full = (k0 + 63 <= wq0);   // wave-uniform (min row = wq0)
#pragma unroll
      for (int i = 0; i < 4; ++i) {
        int qr = wq0 + quad * 4 + i;
        float e[4];
#pragma unroll
        for (int ni = 0; ni < 4; ++ni) {
          float x = sc[ni][i];
          if (!full) x = (k0 + ni * 16 + l15 <= qr) ? x : -1e30f;
          e[ni] = __builtin_amdgcn_exp2f(x);
        }
        lrow[i] += (e[0] + e[1]) + (e[2] + e[3]);
        int prow = (quad * 4 + i) * LDP;
#pragma unroll
        for (int ni = 0; ni < 4; ++ni)
          Pl[wave][prow + ni * 16 + l15] = (bf16)e[ni];
      }
      asm volatile("s_waitcnt lgkmcnt(0)" ::: "memory");
      // PV: P[16x64] @ V[64x64]
#pragma unroll
      for (int kk = 0; kk < 2; ++kk) {
        int kbase = kk * 32 + quad * 8;
        bf16x8 pf = *(const bf16x8*)(&Pl[wave][(l15) * LDP + kbase]);
#pragma unroll
        for (int ni = 0; ni < 4; ++ni) {
          int dd = ni * 16 + l15, u = kk * 4 + quad;
          bf16x8 vf = *(const bf16x8*)(&Vl[dd * 64 + ((u ^ (dd & 7)) * 8)]);
          oacc[ni] = __builtin_amdgcn_mfma_f32_16x16x32_bf16(pf, vf, oacc[ni], 0, 0, 0);
        }
      }
    }
    // epilogue: reduce l across the 16-lane column groups, write Y bf16
#pragma unroll
    for (int i = 0; i < 4; ++i) {
      float rs = lrow[i];
#pragma unroll
      for (int off = 8; off; off >>= 1) rs += __shfl_xor(rs, off, 16);
      float inv = 1.0f / rs;
      int qr = wq0 + quad * 4 + i;
      bf16* dst = Y + ((long)(b * SEQ + qr)) * EMB + h * HD;
#pragma unroll
      for (int ni = 0; ni < 4; ++ni)
        dst[ni * 16 + l15] = (bf16)(oacc[ni][i] * inv);
    }
  }
}

extern "C" void kernel_launch(void* const* d_in, const int* in_sizes, int n_in,
                              void* d_out, int out_size, void* d_ws, size_t ws_size,
                              hipStream_t stream) {
  const float* x      = (const float*)d_in[0];
  const float* W_attn = (const float*)d_in[1];
  const float* b_attn = (const float*)d_in[2];
  const float* W_proj = (const float*)d_in[3];
  const float* b_proj = (const float*)d_in[4];
  float* out = (float*)d_out;
  char* ws = (char*)d_ws;
  bf16* xb  = (bf16*)(ws);                 // 16.78 MB
  bf16* WaT = (bf16*)(ws + 16777216);      //  6.29 MB
  bf16* WpT = (bf16*)(ws + 23068672);      //  2.10 MB
  bf16* Qb  = (bf16*)(ws + 25165824);      // 16.78 MB (pre-scaled)
  bf16* Kb  = (bf16*)(ws + 41943040);      // 16.78 MB
  bf16* Vtb = (bf16*)(ws + 58720256);      // 16.78 MB (transposed [b,h,d,s])
  bf16* Yb  = (bf16*)(ws + 75497472);      // 16.78 MB

  cvt_f32_bf16<<<8192, 256, 0, stream>>>(x, xb, BATCH * SEQ * EMB);
  transpose_cvt2<<<dim3(128, 32), 256, 0, stream>>>(W_attn, W_proj, WaT, WpT);
  gemm_qkv<<<512, 512, 0, stream>>>(xb, WaT, b_attn, Qb, Kb, Vtb);
  attn<<<1024, 256, 0, stream>>>(Qb, Kb, Vtb, Yb);
  gemm_proj<<<1024, 256, 0, stream>>>(Yb, WpT, b_proj, out);
}

// Round 11
// 258.920 us; speedup vs baseline: 1.0132x; 1.0132x over previous
//
#include <hip/hip_runtime.h>

// CausalSelfAttention: x[4,2048,1024] fp32 -> out fp32
// Pipeline (all bf16 MFMA, fp32 accum):
//  1) prep: cvt x->bf16 AND transpose+cvt W_attn/W_proj, ONE merged launch
//  2) gemm8p (128x256 tile, BK=32, 2-phase counted-vmcnt, 768 blocks,
//     256 thr, launch_bounds(256,2)) -> Q (pre-scaled 0.125*log2e), K,
//     V TRANSPOSED [b,h,d,s] (scatter)      [best bound: <76.3us, R6]
//  3) flash attention: 128 q-rows/block (4 waves x 32), 512 blocks, 2-pass
//     (st, 15-st), single-buffered K/V      [best point: 76.3us, R6]
//  4) gemm_proj (128x64 tile, 1024 blocks, 3/CU) + bias -> out fp32 (~35us)
//
// R11 post-mortem of R10 (262.3us; gemm_qkv 128x384 no better than gemm8p):
//   Two meta-findings from R6-R10:
//   (a) Harness TOTAL noise is +/-15us (R6->R7 changed only attn for the
//       WORSE yet total "improved" 16us). Judge per-dispatch times only.
//   (b) attn is pinned 76-80us across ALL structural variants (occupancy
//       19->36%, dbuf, 16/32-row waves). Fitting R6 (18.4K full block-tiles
//       @76.3) vs R9 (33.8K half block-tiles @80.4) gives ~0.3ns/round ->
//       time is proportional to PER-ELEMENT softmax/Pl/PV instruction work,
//       not rounds/occupancy/DS-reads. The lever is the in-register-softmax
//       rewrite (T12 swapped-operand) - a dedicated-round risk.
//   THIS ROUND: recover empirical best of each component (no experiments):
//   Round-6 gemm8p + Round-6 attn + R0 proj; merge cvt+transpose into one
//   launch (independent work, removes one stream serialization boundary).
//
// gemm8p schedule (guide T3+T4+T5, counted vmcnt, never 0 in loop):
//   P0 {RD_A x8, RD_B 0-1, issue A1/B0/B1/B2(t+1), BAR, setprio1, 16 MFMA,
//       setprio0, BAR}
//   P1 {RD_B 2-3, issue B3(t+1)/A0(t+2), vmcnt(1), BAR, setprio1, 16 MFMA,
//       setprio0, BAR}
//   launch_bounds(256,2): reg cap 256 >= ~196 working set (R5 lesson:
//   (256,3) caps at ~170 -> accumulator spill -> 557MB WRITE_SIZE).
// Rotation swizzle (conflict-free, verified R3): writer thread t loads
//   global chunk ((t&3)-((t>>3)&3))&3 into slot t&3; reader slot
//   (quad+(l15>>1))&3. Bank-quad covers all 8 quads 2x over 16 lanes ->
//   2-way = free (m136).
// MFMA 16x16x32 bf16 layouts (HW-verified per guide):
//   A: a[j] = A[m=lane&15][k=quad*8+j]  (quad=lane>>4)
//   B: b[j] = B[k=quad*8+j][n=lane&15]  (from Bt[n][k] read at row n)
//   C/D: c[i] = D[row=quad*4+i][col=lane&15]

#define BATCH 4
#define SEQ   2048
#define EMB   1024
#define NH    16
#define HD    64

typedef __bf16 bf16;
typedef __bf16 bf16x8 __attribute__((ext_vector_type(8)));
typedef float  f32x4  __attribute__((ext_vector_type(4)));

// direct global->LDS 16B copy: LDS dest is wave-uniform base + lane*16
__device__ __forceinline__ void ld_lds16(const void* g, void* l) {
  __builtin_amdgcn_global_load_lds(
      (const __attribute__((address_space(1))) void*)g,
      (__attribute__((address_space(3))) void*)l, 16, 0, 0);
}

// ---------------- prep: cvt x -> bf16  +  transpose/cvt both weights -------
// grid = 8192 (cvt) + 4096 (transpose, 128x32) = 12288 blocks x 256 thr.
// Branch is block-uniform; __syncthreads only in transpose blocks (legal).
__global__ void prep(const float* __restrict__ x, bf16* __restrict__ xb, int n,
                     const float* __restrict__ Wa, const float* __restrict__ Wp,
                     bf16* __restrict__ WaT, bf16* __restrict__ WpT) {
  __shared__ float tile[32][33];
  int bid = blockIdx.x;
  if (bid < 8192) {
    int i = (bid * 256 + threadIdx.x) * 4;
    if (i + 3 < n) {
      float4 v = *(const float4*)(x + i);
      bf16 o0 = (bf16)v.x, o1 = (bf16)v.y, o2 = (bf16)v.z, o3 = (bf16)v.w;
      xb[i] = o0; xb[i+1] = o1; xb[i+2] = o2; xb[i+3] = o3;
    }
    return;
  }
  int tb = bid - 8192;
  int bx = tb & 127;            // [0,128): n0-block
  int byk = tb >> 7;            // [0,32):  k0-block
  const float* W; bf16* WT; int N;
  if (bx < 96) { W = Wa; WT = WaT; N = 3072; }
  else         { W = Wp; WT = WpT; N = 1024; bx -= 96; }
  int n0 = bx * 32, k0 = byk * 32;
  int tx = threadIdx.x & 31, ty = threadIdx.x >> 5;
#pragma unroll
  for (int r = 0; r < 4; r++) {
    int k = k0 + ty + r * 8;
    tile[ty + r * 8][tx] = W[(long)k * N + n0 + tx];
  }
  __syncthreads();
#pragma unroll
  for (int r = 0; r < 4; r++) {
    int nn = n0 + ty + r * 8;
    WT[(long)nn * EMB + k0 + tx] = (bf16)tile[tx][ty + r * 8];
  }
}

#define QSCALE 0.18033688f   // (1/8) * log2(e)

// ---------------- 128x256 phase-pipelined QKV GEMM (Round-6 version) -------
// A[8192][1024] bf16 x Bt[3072][1024] bf16 + bias -> Q/K/V.
// Grid 768 x 256 thr (4 waves, 1Mx4N; wave = 128x64).
__global__ __launch_bounds__(256, 2) void gemm8p(
    const bf16* __restrict__ A, const bf16* __restrict__ Bt,
    const float* __restrict__ bias,
    bf16* __restrict__ q, bf16* __restrict__ k, bf16* __restrict__ v)
{
  __shared__ __align__(16) bf16 lds[24576];   // A[2][4096] | B[2][8192] = 48KB
  int lin = blockIdx.x;
  int xcd = lin & 7, s = lin >> 3;
  int by = xcd * 8 + (s & 7);        // 64 row-blocks = 8 XCD x 8 (A-panel L2 affinity)
  int bx = s >> 3;                   // 12 col-blocks
  int m0 = by * 128, n0 = bx * 256;
  int t = threadIdx.x;
  int wid = t >> 6, lane = t & 63;
  int l15 = lane & 15, quad = lane >> 4;
  int wc = wid;                      // wave tile: all 128 rows x cols wc*64..

  const bf16* Ag = A + (long)m0 * EMB;
  const bf16* Bg = Bt + (long)n0 * EMB;

  f32x4 acc[8][4] = {};
  bf16x8 af[8], bfr[4];
  constexpr int NT = EMB / 32;       // 32 K-tiles
  // physical chunk slot for all frag reads (rotation swizzle; see header)
  int ph8 = ((quad + (l15 >> 1)) & 3) * 8;

#define LDSA(b) (lds + (b) * 4096)
#define LDSB(b) (lds + 8192 + (b) * 8192)

  // stage a 64-row x 32-col quarter: 1 gload_lds per thread (4KB).
  // LDS dest linear; slot p=t&3 receives logical chunk (p-(r>>1))&3.
#define ISSUE64(gbase, rowoff, ldst, ktt)                                      \
  { int r_ = (rowoff) + (t >> 2);                                              \
    int g_ = ((t & 3) - ((t >> 3) & 3)) & 3;                                   \
    ld_lds16(&(gbase)[(long)r_ * EMB + (ktt) + g_ * 8],                        \
             (ldst) + ((rowoff) + wid * 16) * 32); }

#define RD_A(mi) { int r_ = (mi) * 16 + l15;                                   \
    af[mi] = *(const bf16x8*)&Ab[r_ * 32 + ph8]; }
#define RD_B(ni) { int r_ = wc * 64 + (ni) * 16 + l15;                         \
    bfr[ni] = *(const bf16x8*)&Bb[r_ * 32 + ph8]; }

#define FENCE asm volatile("" ::: "memory")
#define BAR   { FENCE; __builtin_amdgcn_s_barrier(); FENCE; }

#define MFMAC(nlo)                                                             \
  { __builtin_amdgcn_s_setprio(1);                                             \
    _Pragma("unroll") for (int mi_ = 0; mi_ < 8; ++mi_)                        \
      _Pragma("unroll") for (int nj_ = 0; nj_ < 2; ++nj_)                      \
        acc[mi_][(nlo) + nj_] = __builtin_amdgcn_mfma_f32_16x16x32_bf16(       \
            af[mi_], bfr[(nlo) + nj_], acc[mi_][(nlo) + nj_], 0, 0, 0);        \
    __builtin_amdgcn_s_setprio(0); }

  // prologue: tile0 complete (6 issues) + A0(tile1) in flight
  ISSUE64(Ag, 0,   LDSA(0), 0);
  ISSUE64(Ag, 64,  LDSA(0), 0);
  ISSUE64(Bg, 0,   LDSB(0), 0);
  ISSUE64(Bg, 64,  LDSB(0), 0);
  ISSUE64(Bg, 128, LDSB(0), 0);
  ISSUE64(Bg, 192, LDSB(0), 0);
  ISSUE64(Ag, 0,   LDSA(1), 32);
  asm volatile("s_waitcnt vmcnt(1)" ::: "memory");
  BAR;

#pragma unroll 2
  for (int tt = 0; tt < NT; ++tt) {
    const bf16* Ab = LDSA(tt & 1);
    const bf16* Bb = LDSB(tt & 1);
    bf16* An = LDSA((tt + 1) & 1);
    bf16* Bn = LDSB((tt + 1) & 1);
    bf16* Ac = LDSA(tt & 1);                         // A0(t+2): (tt+2)&1==tt&1
    int kn  = (tt + 1 < NT ? tt + 1 : NT - 1) * 32;  // clamped at tail:
    int kn2 = (tt + 2 < NT ? tt + 2 : NT - 1) * 32;  // dummy identical reload

    // P0: all A frags + low B frags; prefetch A1/B0/B1/B2(t+1)
#pragma unroll
    for (int mi = 0; mi < 8; ++mi) RD_A(mi);
    RD_B(0); RD_B(1);
    ISSUE64(Ag, 64,  An, kn);
    ISSUE64(Bg, 0,   Bn, kn);
    ISSUE64(Bg, 64,  Bn, kn);
    ISSUE64(Bg, 128, Bn, kn);
    BAR; MFMAC(0); BAR;
    // P1: high B frags; prefetch B3(t+1) + A0(t+2) (A reads done in P0)
    RD_B(2); RD_B(3);
    ISSUE64(Bg, 192, Bn, kn);
    ISSUE64(Ag, 0,   Ac, kn2);
    asm volatile("s_waitcnt vmcnt(1)" ::: "memory");  // t+1 fully landed
    BAR; MFMAC(2); BAR;
  }

  asm volatile("s_waitcnt vmcnt(0)" ::: "memory");   // drain clamped DMAs
  __syncthreads();

  // ---------------- epilogue: Q (scaled) / K / V^T scatter ----------------
  int which = bx >> 2;   // tile lies entirely in Q, K, or V
  if (which < 2) {
    bf16* dst = (which == 0) ? q : k;
    float scale = (which == 0) ? QSCALE : 1.0f;
#pragma unroll
    for (int mi = 0; mi < 8; ++mi)
#pragma unroll
      for (int ni = 0; ni < 4; ++ni) {
        int gcol = n0 + wc * 64 + ni * 16 + l15;
        float bv = bias[gcol];
        int e = gcol & 1023, h = e >> 6, d = e & 63;
#pragma unroll
        for (int i = 0; i < 4; ++i) {
          int grow = m0 + mi * 16 + quad * 4 + i;
          int b = grow >> 11, ss = grow & 2047;
          dst[(((long)b * NH + h) * SEQ + ss) * HD + d] =
              (bf16)((acc[mi][ni][i] + bv) * scale);
        }
      }
  } else {
    // V^T scatter (proven: WRITE_SIZE stays ideal, L2 absorbs)
#pragma unroll
    for (int mi = 0; mi < 8; ++mi)
#pragma unroll
      for (int ni = 0; ni < 4; ++ni) {
        int gcol = n0 + wc * 64 + ni * 16 + l15;
        float bv = bias[gcol];
        int e = gcol & 1023, h = e >> 6, d = e & 63;
#pragma unroll
        for (int i = 0; i < 4; ++i) {
          int grow = m0 + mi * 16 + quad * 4 + i;
          int b = grow >> 11, ss = grow & 2047;
          v[(((long)b * NH + h) * HD + d) * SEQ + ss] =
              (bf16)(acc[mi][ni][i] + bv);
        }
      }
  }
#undef LDSA
#undef LDSB
#undef ISSUE64
#undef RD_A
#undef RD_B
#undef MFMAC
}

// ---------------- proj GEMM (R0 known-good): 128x64 tile, 3 blocks/CU ------
__global__ __launch_bounds__(256, 3) void gemm_proj(
    const bf16* __restrict__ A, const bf16* __restrict__ Bt,
    const float* __restrict__ bias, float* __restrict__ out)
{
  __shared__ __align__(16) bf16 Al[128 * 64];
  __shared__ __align__(16) bf16 Bl[64 * 64];
  int lin = blockIdx.x;
  int xcd = lin & 7, s = lin >> 3;
  int bx = s >> 3, by = xcd * 8 + (s & 7);
  int m0 = by * 128;
  int n0 = bx * 64;
  int t = threadIdx.x;
  int wave = t >> 6, lane = t & 63;
  int l15 = lane & 15, quad = lane >> 4;
  int wm = (wave & 1) * 64, wn = (wave >> 1) * 32;

  f32x4 acc[4][2] = {};

  for (int kt = 0; kt < EMB; kt += 64) {
    __syncthreads();
#pragma unroll
    for (int it = 0; it < 4; ++it) {         // A: 128 rows x 8 units
      int c = it * 256 + t;
      int row = c >> 3, u = c & 7;
      ld_lds16(&A[(long)(m0 + row) * EMB + kt + ((u ^ (row & 7)) * 8)],
               &Al[(it * 256 + wave * 64) * 8]);
    }
    {
      int c = t;                              // B: 64 rows x 8 units
      int row = c >> 3, u = c & 7;
      ld_lds16(&Bt[(long)(n0 + row) * EMB + kt + ((u ^ (row & 7)) * 8)],
               &Bl[(wave * 64) * 8]);
      c = 256 + t;
      row = c >> 3; u = c & 7;
      ld_lds16(&Bt[(long)(n0 + row) * EMB + kt + ((u ^ (row & 7)) * 8)],
               &Bl[(256 + wave * 64) * 8]);
    }
    __syncthreads();
#pragma unroll
    for (int ks = 0; ks < 2; ++ks) {
      bf16x8 af[4], bfr[2];
#pragma unroll
      for (int i = 0; i < 4; ++i) {
        int r = wm + i * 16 + l15;
        af[i] = *(const bf16x8*)(&Al[r * 64 + (((ks * 4 + quad) ^ (r & 7)) * 8)]);
      }
#pragma unroll
      for (int i = 0; i < 2; ++i) {
        int r = wn + i * 16 + l15;
        bfr[i] = *(const bf16x8*)(&Bl[r * 64 + (((ks * 4 + quad) ^ (r & 7)) * 8)]);
      }
#pragma unroll
      for (int mi = 0; mi < 4; ++mi)
#pragma unroll
        for (int ni = 0; ni < 2; ++ni)
          acc[mi][ni] = __builtin_amdgcn_mfma_f32_16x16x32_bf16(af[mi], bfr[ni], acc[mi][ni], 0, 0, 0);
    }
  }

#pragma unroll
  for (int mi = 0; mi < 4; ++mi)
#pragma unroll
    for (int ni = 0; ni < 2; ++ni) {
      int gcol = n0 + wn + ni * 16 + l15;
      float bv = bias[gcol];
#pragma unroll
      for (int i = 0; i < 4; ++i) {
        int grow = m0 + wm + mi * 16 + quad * 4 + i;
        out[(long)grow * EMB + gcol] = acc[mi][ni][i] + bv;
      }
    }
}

// ---------------- flash attention (Round-6 version: best point 76.3us) -----
// 1D grid 512 blocks; block 256 = 4 waves x 32 q-rows = 128-row strip.
// Decode: xcd=L&7, a=L>>3; head = xcd + 8*(a&7); strip = a>>3; block runs
// strips st and 15-st (pass loop). 64-key tiles staged once per block/tile.
#define LDP 72   // P row stride (elems): conflict-free, 16B-aligned

__global__ __launch_bounds__(256, 2) void attn(
    const bf16* __restrict__ Q, const bf16* __restrict__ K,
    const bf16* __restrict__ Vt, bf16* __restrict__ Y)
{
  __shared__ __align__(16) bf16 Kl[64 * 64];        // 8 KB
  __shared__ __align__(16) bf16 Vl[64 * 64];        // 8 KB
  __shared__ __align__(16) bf16 Pl[4][32 * LDP];    // 18 KB, per-wave
  int L = blockIdx.x;
  int a = L >> 3;
  int hd = (L & 7) + 8 * (a & 7);
  int st = a >> 3;
  int b = hd >> 4, h = hd & 15;
  const bf16* Qp  = Q  + (((long)b * NH + h) * SEQ) * HD;
  const bf16* Kp  = K  + (((long)b * NH + h) * SEQ) * HD;
  const bf16* Vtp = Vt + (((long)b * NH + h) * HD) * SEQ;
  int t = threadIdx.x, wave = t >> 6, lane = t & 63;
  int l15 = lane & 15, quad = lane >> 4;

#pragma unroll 1
  for (int pass = 0; pass < 2; ++pass) {
    int q0 = (pass == 0) ? st * 128 : (SEQ - 128) - st * 128;
    int wq0 = q0 + wave * 32;

    // Q fragments: m-frag m covers rows wq0+m*16 .. +15; k split 0/32
    bf16x8 qf[2][2];
#pragma unroll
    for (int m = 0; m < 2; ++m) {
      const bf16* qrow = Qp + (long)(wq0 + m * 16 + l15) * HD + quad * 8;
      qf[m][0] = *(const bf16x8*)(qrow);
      qf[m][1] = *(const bf16x8*)(qrow + 32);
    }
    float lrow[2][4] = {};
    f32x4 oacc[2][4] = {};

    int ntiles = q0 / 64 + 2;     // block's 128 rows need tiles through q0+127
#pragma unroll 1
    for (int kt = 0; kt < ntiles; ++kt) {
      int k0 = kt * 64;
      __syncthreads();
      // stage K [key][d], V^T [d][key]: unit row*8+u holds chunk u^(row&7)
#pragma unroll
      for (int it = 0; it < 2; ++it) {
        int cu = it * 256 + t;
        int row = cu >> 3, u = cu & 7;
        ld_lds16(&Kp[(long)(k0 + row) * HD + ((u ^ (row & 7)) * 8)],
                 &Kl[(it * 256 + wave * 64) * 8]);
        ld_lds16(&Vtp[(long)row * SEQ + k0 + ((u ^ (row & 7)) * 8)],
                 &Vl[(it * 256 + wave * 64) * 8]);
      }
      __syncthreads();
      if (k0 > wq0 + 31) continue;   // wave's rows all masked for this tile

      // scores: S[32q x 64k]; kfr register-shared across both m-frags
      f32x4 sc[2][4] = {};
#pragma unroll
      for (int kk = 0; kk < 2; ++kk) {
#pragma unroll
        for (int ni = 0; ni < 4; ++ni) {
          int r = ni * 16 + l15, u = kk * 4 + quad;
          bf16x8 kfr = *(const bf16x8*)(&Kl[r * 64 + ((u ^ (r & 7)) * 8)]);
          sc[0][ni] = __builtin_amdgcn_mfma_f32_16x16x32_bf16(qf[0][kk], kfr, sc[0][ni], 0, 0, 0);
          sc[1][ni] = __builtin_amdgcn_mfma_f32_16x16x32_bf16(qf[1][kk], kfr, sc[1][ni], 0, 0, 0);
        }
      }

      bool full = (k0 + 63 <= wq0);   // wave-uniform (min row = wq0)
#pragma unroll
      for (int m = 0; m < 2; ++m) {
#pragma unroll
        for (int i = 0; i < 4; ++i) {
          int qr = wq0 + m * 16 + quad * 4 + i;
          float e[4];
#pragma unroll
          for (int ni = 0; ni < 4; ++ni) {
            float x = sc[m][ni][i];
            if (!full) x = (k0 + ni * 16 + l15 <= qr) ? x : -1e30f;
            e[ni] = __builtin_amdgcn_exp2f(x);
          }
          lrow[m][i] += (e[0] + e[1]) + (e[2] + e[3]);
          int prow = (m * 16 + quad * 4 + i) * LDP;
#pragma unroll
          for (int ni = 0; ni < 4; ++ni)
            Pl[wave][prow + ni * 16 + l15] = (bf16)e[ni];
        }
      }
      asm volatile("s_waitcnt lgkmcnt(0)" ::: "memory");
      // PV: P[32x64] @ V[64x64]; vf register-shared across both m-frags
#pragma unroll
      for (int kk = 0; kk < 2; ++kk) {
        int kbase = kk * 32 + quad * 8;
        bf16x8 pf0 = *(const bf16x8*)(&Pl[wave][(l15) * LDP + kbase]);
        bf16x8 pf1 = *(const bf16x8*)(&Pl[wave][(16 + l15) * LDP + kbase]);
#pragma unroll
        for (int ni = 0; ni < 4; ++ni) {
          int dd = ni * 16 + l15, u = kk * 4 + quad;
          bf16x8 vf = *(const bf16x8*)(&Vl[dd * 64 + ((u ^ (dd & 7)) * 8)]);
          oacc[0][ni] = __builtin_amdgcn_mfma_f32_16x16x32_bf16(pf0, vf, oacc[0][ni], 0, 0, 0);
          oacc[1][ni] = __builtin_amdgcn_mfma_f32_16x16x32_bf16(pf1, vf, oacc[1][ni], 0, 0, 0);
        }
      }
    }
    // epilogue: reduce l across the 16-lane column groups, write Y bf16
#pragma unroll
    for (int m = 0; m < 2; ++m) {
#pragma unroll
      for (int i = 0; i < 4; ++i) {
        float rs = lrow[m][i];
#pragma unroll
        for (int off = 8; off; off >>= 1) rs += __shfl_xor(rs, off, 16);
        float inv = 1.0f / rs;
        int qr = wq0 + m * 16 + quad * 4 + i;
        bf16* dst = Y + ((long)(b * SEQ + qr)) * EMB + h * HD;
#pragma unroll
        for (int ni = 0; ni < 4; ++ni)
          dst[ni * 16 + l15] = (bf16)(oacc[m][ni][i] * inv);
      }
    }
  }
}

extern "C" void kernel_launch(void* const* d_in, const int* in_sizes, int n_in,
                              void* d_out, int out_size, void* d_ws, size_t ws_size,
                              hipStream_t stream) {
  const float* x      = (const float*)d_in[0];
  const float* W_attn = (const float*)d_in[1];
  const float* b_attn = (const float*)d_in[2];
  const float* W_proj = (const float*)d_in[3];
  const float* b_proj = (const float*)d_in[4];
  float* out = (float*)d_out;
  char* ws = (char*)d_ws;
  bf16* xb  = (bf16*)(ws);                 // 16.78 MB
  bf16* WaT = (bf16*)(ws + 16777216);      //  6.29 MB
  bf16* WpT = (bf16*)(ws + 23068672);      //  2.10 MB
  bf16* Qb  = (bf16*)(ws + 25165824);      // 16.78 MB (pre-scaled)
  bf16* Kb  = (bf16*)(ws + 41943040);      // 16.78 MB
  bf16* Vtb = (bf16*)(ws + 58720256);      // 16.78 MB (transposed [b,h,d,s])
  bf16* Yb  = (bf16*)(ws + 75497472);      // 16.78 MB

  prep<<<12288, 256, 0, stream>>>(x, xb, BATCH * SEQ * EMB,
                                  W_attn, W_proj, WaT, WpT);
  gemm8p<<<768, 256, 0, stream>>>(xb, WaT, b_attn, Qb, Kb, Vtb);
  attn<<<512, 256, 0, stream>>>(Qb, Kb, Vtb, Yb);
  gemm_proj<<<1024, 256, 0, stream>>>(Yb, WpT, b_proj, out);
}

// Round 12
// 232.788 us; speedup vs baseline: 1.1269x; 1.1123x over previous
//
#include <hip/hip_runtime.h>

// CausalSelfAttention: x[4,2048,1024] fp32 -> out fp32
// Pipeline (all bf16 MFMA, fp32 accum):
//  1) prep: cvt x->bf16 AND transpose+cvt W_attn/W_proj, ONE merged launch
//  2) gemm8p (128x256 tile, BK=32, 2-phase counted-vmcnt, 768 blocks)
//     -> Q (pre-scaled 0.125*log2e), K, V TRANSPOSED [b,h,d,s]
//  3) flash attention, IN-REGISTER SOFTMAX (T12-analog, this round):
//     swapped QK^T (A=K, B=Q) + custom key<->MFMA-row map makes each lane
//     hold S[q = m*16+l15][keys quad*8+0..7 (+32kk)] = EXACTLY the swapped-PV
//     B-fragment -> P never touches LDS. Removes per wave-tile: 32
//     ds_write_b16 + 4 ds_read_b128 + lgkmcnt(0) drain (~45% of DS budget,
//     the measured ~1360cyc/CU-tile binder). LDS 34.8 -> 16.4KB.
//  4) gemm_proj (128x64 tile, 1024 blocks, 3/CU) + bias -> out fp32
//
// R12 analysis (R11 = clean baseline, attn 77.0us):
//   attn DS budget/wave-tile: K 8xb128 + V 8xb128 + P-trip (32 write_b16 +
//   4 read_b128 + lgkm drain) + 4 gload = ~44 DS ops = ~1400cyc/CU-tile,
//   matching measured. P-trip is the serialization + ~45% of DS.
//   KEY-MAP DERIVATION (verified bijective): QK swapped gives C[key][q];
//   C-row r_c = quad*4+i is fed by A-row r=r_c; choose A-frag f to read
//   K at key(r,f) = 32*(f>>1) + (r>>2)*8 + (f&1)*4 + (r&3). Then lane
//   (quad,l15) sc[m][f][i] = S[key = k0+32*(f>>1)+quad*8+(f&1)*4+i][q =
//   wq0+m*16+l15]: f pairs (2kk,2kk+1) give keys 32kk+quad*8+{0..7} = the
//   PV B-frag b[j]=P[key=32kk+quad*8+j][q=l15], j<4 from f even i=j, j>=4
//   from f odd i=j-4. V^T A-frag read from Vl identical to old vf read.
//   Row-sum: lane partials over its 16 keys -> epilogue shfl_xor(16,32).
//   O lands as O[q=m*16+l15][d=ni*16+quad*4+i] -> packed 8B stores.
//
// gemm8p schedule (guide T3+T4+T5, counted vmcnt, never 0 in loop):
//   P0 {RD_A x8, RD_B 0-1, issue A1/B0/B1/B2(t+1), BAR, setprio1, 16 MFMA,
//       setprio0, BAR}
//   P1 {RD_B 2-3, issue B3(t+1)/A0(t+2), vmcnt(1), BAR, setprio1, 16 MFMA,
//       setprio0, BAR}
//   launch_bounds(256,2): reg cap 256 >= ~196 working set (R5 lesson:
//   (256,3) caps at ~170 -> accumulator spill -> 557MB WRITE_SIZE).
// Rotation swizzle (conflict-free, verified R3): writer thread t loads
//   global chunk ((t&3)-((t>>3)&3))&3 into slot t&3; reader slot
//   (quad+(l15>>1))&3.
// MFMA 16x16x32 bf16 layouts (HW-verified per guide):
//   A: a[j] = A[m=lane&15][k=quad*8+j]  (quad=lane>>4)
//   B: b[j] = B[k=quad*8+j][n=lane&15]
//   C/D: c[i] = D[row=quad*4+i][col=lane&15]

#define BATCH 4
#define SEQ   2048
#define EMB   1024
#define NH    16
#define HD    64

typedef __bf16 bf16;
typedef __bf16 bf16x8 __attribute__((ext_vector_type(8)));
typedef __bf16 bf16x4 __attribute__((ext_vector_type(4)));
typedef float  f32x4  __attribute__((ext_vector_type(4)));

// direct global->LDS 16B copy: LDS dest is wave-uniform base + lane*16
__device__ __forceinline__ void ld_lds16(const void* g, void* l) {
  __builtin_amdgcn_global_load_lds(
      (const __attribute__((address_space(1))) void*)g,
      (__attribute__((address_space(3))) void*)l, 16, 0, 0);
}

// ---------------- prep: cvt x -> bf16  +  transpose/cvt both weights -------
// grid = 8192 (cvt) + 4096 (transpose, 128x32) = 12288 blocks x 256 thr.
__global__ void prep(const float* __restrict__ x, bf16* __restrict__ xb, int n,
                     const float* __restrict__ Wa, const float* __restrict__ Wp,
                     bf16* __restrict__ WaT, bf16* __restrict__ WpT) {
  __shared__ float tile[32][33];
  int bid = blockIdx.x;
  if (bid < 8192) {
    int i = (bid * 256 + threadIdx.x) * 4;
    if (i + 3 < n) {
      float4 v = *(const float4*)(x + i);
      bf16 o0 = (bf16)v.x, o1 = (bf16)v.y, o2 = (bf16)v.z, o3 = (bf16)v.w;
      xb[i] = o0; xb[i+1] = o1; xb[i+2] = o2; xb[i+3] = o3;
    }
    return;
  }
  int tb = bid - 8192;
  int bx = tb & 127;            // [0,128): n0-block
  int byk = tb >> 7;            // [0,32):  k0-block
  const float* W; bf16* WT; int N;
  if (bx < 96) { W = Wa; WT = WaT; N = 3072; }
  else         { W = Wp; WT = WpT; N = 1024; bx -= 96; }
  int n0 = bx * 32, k0 = byk * 32;
  int tx = threadIdx.x & 31, ty = threadIdx.x >> 5;
#pragma unroll
  for (int r = 0; r < 4; r++) {
    int k = k0 + ty + r * 8;
    tile[ty + r * 8][tx] = W[(long)k * N + n0 + tx];
  }
  __syncthreads();
#pragma unroll
  for (int r = 0; r < 4; r++) {
    int nn = n0 + ty + r * 8;
    WT[(long)nn * EMB + k0 + tx] = (bf16)tile[tx][ty + r * 8];
  }
}

#define QSCALE 0.18033688f   // (1/8) * log2(e)

// ---------------- 128x256 phase-pipelined QKV GEMM (Round-6 version) -------
// A[8192][1024] bf16 x Bt[3072][1024] bf16 + bias -> Q/K/V.
// Grid 768 x 256 thr (4 waves, 1Mx4N; wave = 128x64).
__global__ __launch_bounds__(256, 2) void gemm8p(
    const bf16* __restrict__ A, const bf16* __restrict__ Bt,
    const float* __restrict__ bias,
    bf16* __restrict__ q, bf16* __restrict__ k, bf16* __restrict__ v)
{
  __shared__ __align__(16) bf16 lds[24576];   // A[2][4096] | B[2][8192] = 48KB
  int lin = blockIdx.x;
  int xcd = lin & 7, s = lin >> 3;
  int by = xcd * 8 + (s & 7);        // 64 row-blocks = 8 XCD x 8 (A-panel L2 affinity)
  int bx = s >> 3;                   // 12 col-blocks
  int m0 = by * 128, n0 = bx * 256;
  int t = threadIdx.x;
  int wid = t >> 6, lane = t & 63;
  int l15 = lane & 15, quad = lane >> 4;
  int wc = wid;                      // wave tile: all 128 rows x cols wc*64..

  const bf16* Ag = A + (long)m0 * EMB;
  const bf16* Bg = Bt + (long)n0 * EMB;

  f32x4 acc[8][4] = {};
  bf16x8 af[8], bfr[4];
  constexpr int NT = EMB / 32;       // 32 K-tiles
  // physical chunk slot for all frag reads (rotation swizzle; see header)
  int ph8 = ((quad + (l15 >> 1)) & 3) * 8;

#define LDSA(b) (lds + (b) * 4096)
#define LDSB(b) (lds + 8192 + (b) * 8192)

  // stage a 64-row x 32-col quarter: 1 gload_lds per thread (4KB).
  // LDS dest linear; slot p=t&3 receives logical chunk (p-(r>>1))&3.
#define ISSUE64(gbase, rowoff, ldst, ktt)                                      \
  { int r_ = (rowoff) + (t >> 2);                                              \
    int g_ = ((t & 3) - ((t >> 3) & 3)) & 3;                                   \
    ld_lds16(&(gbase)[(long)r_ * EMB + (ktt) + g_ * 8],                        \
             (ldst) + ((rowoff) + wid * 16) * 32); }

#define RD_A(mi) { int r_ = (mi) * 16 + l15;                                   \
    af[mi] = *(const bf16x8*)&Ab[r_ * 32 + ph8]; }
#define RD_B(ni) { int r_ = wc * 64 + (ni) * 16 + l15;                         \
    bfr[ni] = *(const bf16x8*)&Bb[r_ * 32 + ph8]; }

#define FENCE asm volatile("" ::: "memory")
#define BAR   { FENCE; __builtin_amdgcn_s_barrier(); FENCE; }

#define MFMAC(nlo)                                                             \
  { __builtin_amdgcn_s_setprio(1);                                             \
    _Pragma("unroll") for (int mi_ = 0; mi_ < 8; ++mi_)                        \
      _Pragma("unroll") for (int nj_ = 0; nj_ < 2; ++nj_)                      \
        acc[mi_][(nlo) + nj_] = __builtin_amdgcn_mfma_f32_16x16x32_bf16(       \
            af[mi_], bfr[(nlo) + nj_], acc[mi_][(nlo) + nj_], 0, 0, 0);        \
    __builtin_amdgcn_s_setprio(0); }

  // prologue: tile0 complete (6 issues) + A0(tile1) in flight
  ISSUE64(Ag, 0,   LDSA(0), 0);
  ISSUE64(Ag, 64,  LDSA(0), 0);
  ISSUE64(Bg, 0,   LDSB(0), 0);
  ISSUE64(Bg, 64,  LDSB(0), 0);
  ISSUE64(Bg, 128, LDSB(0), 0);
  ISSUE64(Bg, 192, LDSB(0), 0);
  ISSUE64(Ag, 0,   LDSA(1), 32);
  asm volatile("s_waitcnt vmcnt(1)" ::: "memory");
  BAR;

#pragma unroll 2
  for (int tt = 0; tt < NT; ++tt) {
    const bf16* Ab = LDSA(tt & 1);
    const bf16* Bb = LDSB(tt & 1);
    bf16* An = LDSA((tt + 1) & 1);
    bf16* Bn = LDSB((tt + 1) & 1);
    bf16* Ac = LDSA(tt & 1);                         // A0(t+2): (tt+2)&1==tt&1
    int kn  = (tt + 1 < NT ? tt + 1 : NT - 1) * 32;  // clamped at tail:
    int kn2 = (tt + 2 < NT ? tt + 2 : NT - 1) * 32;  // dummy identical reload

    // P0: all A frags + low B frags; prefetch A1/B0/B1/B2(t+1)
#pragma unroll
    for (int mi = 0; mi < 8; ++mi) RD_A(mi);
    RD_B(0); RD_B(1);
    ISSUE64(Ag, 64,  An, kn);
    ISSUE64(Bg, 0,   Bn, kn);
    ISSUE64(Bg, 64,  Bn, kn);
    ISSUE64(Bg, 128, Bn, kn);
    BAR; MFMAC(0); BAR;
    // P1: high B frags; prefetch B3(t+1) + A0(t+2) (A reads done in P0)
    RD_B(2); RD_B(3);
    ISSUE64(Bg, 192, Bn, kn);
    ISSUE64(Ag, 0,   Ac, kn2);
    asm volatile("s_waitcnt vmcnt(1)" ::: "memory");  // t+1 fully landed
    BAR; MFMAC(2); BAR;
  }

  asm volatile("s_waitcnt vmcnt(0)" ::: "memory");   // drain clamped DMAs
  __syncthreads();

  // ---------------- epilogue: Q (scaled) / K / V^T scatter ----------------
  int which = bx >> 2;   // tile lies entirely in Q, K, or V
  if (which < 2) {
    bf16* dst = (which == 0) ? q : k;
    float scale = (which == 0) ? QSCALE : 1.0f;
#pragma unroll
    for (int mi = 0; mi < 8; ++mi)
#pragma unroll
      for (int ni = 0; ni < 4; ++ni) {
        int gcol = n0 + wc * 64 + ni * 16 + l15;
        float bv = bias[gcol];
        int e = gcol & 1023, h = e >> 6, d = e & 63;
#pragma unroll
        for (int i = 0; i < 4; ++i) {
          int grow = m0 + mi * 16 + quad * 4 + i;
          int b = grow >> 11, ss = grow & 2047;
          dst[(((long)b * NH + h) * SEQ + ss) * HD + d] =
              (bf16)((acc[mi][ni][i] + bv) * scale);
        }
      }
  } else {
    // V^T scatter (proven: WRITE_SIZE stays ideal, L2 absorbs)
#pragma unroll
    for (int mi = 0; mi < 8; ++mi)
#pragma unroll
      for (int ni = 0; ni < 4; ++ni) {
        int gcol = n0 + wc * 64 + ni * 16 + l15;
        float bv = bias[gcol];
        int e = gcol & 1023, h = e >> 6, d = e & 63;
#pragma unroll
        for (int i = 0; i < 4; ++i) {
          int grow = m0 + mi * 16 + quad * 4 + i;
          int b = grow >> 11, ss = grow & 2047;
          v[(((long)b * NH + h) * HD + d) * SEQ + ss] =
              (bf16)(acc[mi][ni][i] + bv);
        }
      }
  }
#undef LDSA
#undef LDSB
#undef ISSUE64
#undef RD_A
#undef RD_B
#undef MFMAC
}

// ---------------- proj GEMM (R0 known-good): 128x64 tile, 3 blocks/CU ------
__global__ __launch_bounds__(256, 3) void gemm_proj(
    const bf16* __restrict__ A, const bf16* __restrict__ Bt,
    const float* __restrict__ bias, float* __restrict__ out)
{
  __shared__ __align__(16) bf16 Al[128 * 64];
  __shared__ __align__(16) bf16 Bl[64 * 64];
  int lin = blockIdx.x;
  int xcd = lin & 7, s = lin >> 3;
  int bx = s >> 3, by = xcd * 8 + (s & 7);
  int m0 = by * 128;
  int n0 = bx * 64;
  int t = threadIdx.x;
  int wave = t >> 6, lane = t & 63;
  int l15 = lane & 15, quad = lane >> 4;
  int wm = (wave & 1) * 64, wn = (wave >> 1) * 32;

  f32x4 acc[4][2] = {};

  for (int kt = 0; kt < EMB; kt += 64) {
    __syncthreads();
#pragma unroll
    for (int it = 0; it < 4; ++it) {         // A: 128 rows x 8 units
      int c = it * 256 + t;
      int row = c >> 3, u = c & 7;
      ld_lds16(&A[(long)(m0 + row) * EMB + kt + ((u ^ (row & 7)) * 8)],
               &Al[(it * 256 + wave * 64) * 8]);
    }
    {
      int c = t;                              // B: 64 rows x 8 units
      int row = c >> 3, u = c & 7;
      ld_lds16(&Bt[(long)(n0 + row) * EMB + kt + ((u ^ (row & 7)) * 8)],
               &Bl[(wave * 64) * 8]);
      c = 256 + t;
      row = c >> 3; u = c & 7;
      ld_lds16(&Bt[(long)(n0 + row) * EMB + kt + ((u ^ (row & 7)) * 8)],
               &Bl[(256 + wave * 64) * 8]);
    }
    __syncthreads();
#pragma unroll
    for (int ks = 0; ks < 2; ++ks) {
      bf16x8 af[4], bfr[2];
#pragma unroll
      for (int i = 0; i < 4; ++i) {
        int r = wm + i * 16 + l15;
        af[i] = *(const bf16x8*)(&Al[r * 64 + (((ks * 4 + quad) ^ (r & 7)) * 8)]);
      }
#pragma unroll
      for (int i = 0; i < 2; ++i) {
        int r = wn + i * 16 + l15;
        bfr[i] = *(const bf16x8*)(&Bl[r * 64 + (((ks * 4 + quad) ^ (r & 7)) * 8)]);
      }
#pragma unroll
      for (int mi = 0; mi < 4; ++mi)
#pragma unroll
        for (int ni = 0; ni < 2; ++ni)
          acc[mi][ni] = __builtin_amdgcn_mfma_f32_16x16x32_bf16(af[mi], bfr[ni], acc[mi][ni], 0, 0, 0);
    }
  }

#pragma unroll
  for (int mi = 0; mi < 4; ++mi)
#pragma unroll
    for (int ni = 0; ni < 2; ++ni) {
      int gcol = n0 + wn + ni * 16 + l15;
      float bv = bias[gcol];
#pragma unroll
      for (int i = 0; i < 4; ++i) {
        int grow = m0 + wm + mi * 16 + quad * 4 + i;
        out[(long)grow * EMB + gcol] = acc[mi][ni][i] + bv;
      }
    }
}

// ---------------- flash attention: in-register softmax (T12-analog) --------
// 1D grid 512 blocks; block 256 = 4 waves x 32 q-rows = 128-row strip.
// Decode: xcd=L&7, a=L>>3; head = xcd + 8*(a&7); strip = a>>3; block runs
// strips st and 15-st. Swapped QK^T + key<->row map => P stays in registers;
// LDS holds only K and V tiles (16KB). No Pl, no lgkm drain.
__global__ __launch_bounds__(256, 2) void attn(
    const bf16* __restrict__ Q, const bf16* __restrict__ K,
    const bf16* __restrict__ Vt, bf16* __restrict__ Y)
{
  __shared__ __align__(16) bf16 Kl[64 * 64];        // 8 KB
  __shared__ __align__(16) bf16 Vl[64 * 64];        // 8 KB
  int L = blockIdx.x;
  int a = L >> 3;
  int hd = (L & 7) + 8 * (a & 7);
  int st = a >> 3;
  int b = hd >> 4, h = hd & 15;
  const bf16* Qp  = Q  + (((long)b * NH + h) * SEQ) * HD;
  const bf16* Kp  = K  + (((long)b * NH + h) * SEQ) * HD;
  const bf16* Vtp = Vt + (((long)b * NH + h) * HD) * SEQ;
  int t = threadIdx.x, wave = t >> 6, lane = t & 63;
  int l15 = lane & 15, quad = lane >> 4;
  // K-frag row map base (per f): key(r=l15, f) = 32*(f>>1)+(l15>>2)*8+(f&1)*4+(l15&3)
  int rkbase = ((l15 >> 2) << 3) + (l15 & 3);

#pragma unroll 1
  for (int pass = 0; pass < 2; ++pass) {
    int q0 = (pass == 0) ? st * 128 : (SEQ - 128) - st * 128;
    int wq0 = q0 + wave * 32;

    // Q fragments (B-operand now): b[j] = Q[q=wq0+m*16+l15][d=quad*8+j+32kd]
    bf16x8 qf[2][2];
#pragma unroll
    for (int m = 0; m < 2; ++m) {
      const bf16* qrow = Qp + (long)(wq0 + m * 16 + l15) * HD + quad * 8;
      qf[m][0] = *(const bf16x8*)(qrow);
      qf[m][1] = *(const bf16x8*)(qrow + 32);
    }
    float lrow[2] = {};
    f32x4 oacc[2][4] = {};

    int ntiles = q0 / 64 + 2;     // block's 128 rows need tiles through q0+127
#pragma unroll 1
    for (int kt = 0; kt < ntiles; ++kt) {
      int k0 = kt * 64;
      __syncthreads();
      // stage K [key][d], V^T [d][key]: unit row*8+u holds chunk u^(row&7)
#pragma unroll
      for (int it = 0; it < 2; ++it) {
        int cu = it * 256 + t;
        int row = cu >> 3, u = cu & 7;
        ld_lds16(&Kp[(long)(k0 + row) * HD + ((u ^ (row & 7)) * 8)],
                 &Kl[(it * 256 + wave * 64) * 8]);
        ld_lds16(&Vtp[(long)row * SEQ + k0 + ((u ^ (row & 7)) * 8)],
                 &Vl[(it * 256 + wave * 64) * 8]);
      }
      __syncthreads();
      if (k0 > wq0 + 31) continue;   // wave's rows all masked for this tile

      // swapped QK: sc[m][f][i] = S[key=k0+32*(f>>1)+quad*8+(f&1)*4+i][q=wq0+m*16+l15]
      f32x4 sc[2][4] = {};
#pragma unroll
      for (int kd = 0; kd < 2; ++kd) {
#pragma unroll
        for (int f = 0; f < 4; ++f) {
          int rk = ((f >> 1) << 5) + ((f & 1) << 2) + rkbase;
          bf16x8 kf = *(const bf16x8*)(&Kl[rk * 64 + (((kd * 4 + quad) ^ (rk & 7)) * 8)]);
          sc[0][f] = __builtin_amdgcn_mfma_f32_16x16x32_bf16(kf, qf[0][kd], sc[0][f], 0, 0, 0);
          sc[1][f] = __builtin_amdgcn_mfma_f32_16x16x32_bf16(kf, qf[1][kd], sc[1][f], 0, 0, 0);
        }
      }

      bool full = (k0 + 63 <= wq0);   // wave-uniform (min row = wq0)
      bf16x8 pb[2][2];                // PV B-frags: pb[m][kk]
#pragma unroll
      for (int m = 0; m < 2; ++m) {
        int qr = wq0 + m * 16 + l15;
#pragma unroll
        for (int f = 0; f < 4; ++f) {
          int kgb = k0 + ((f >> 1) << 5) + quad * 8 + ((f & 1) << 2);
          float e[4];
#pragma unroll
          for (int i = 0; i < 4; ++i) {
            float x = sc[m][f][i];
            if (!full) x = (kgb + i <= qr) ? x : -1e30f;
            e[i] = __builtin_amdgcn_exp2f(x);
          }
          lrow[m] += (e[0] + e[1]) + (e[2] + e[3]);
#pragma unroll
          for (int i = 0; i < 4; ++i)
            pb[m][f >> 1][((f & 1) << 2) + i] = (bf16)e[i];
        }
      }

      // swapped PV: oacc[m][ni][i] = O[q=wq0+m*16+l15][d=ni*16+quad*4+i]
#pragma unroll
      for (int kp = 0; kp < 2; ++kp) {
#pragma unroll
        for (int ni = 0; ni < 4; ++ni) {
          int dd = ni * 16 + l15;
          bf16x8 vf = *(const bf16x8*)(&Vl[dd * 64 + (((kp * 4 + quad) ^ (dd & 7)) * 8)]);
          oacc[0][ni] = __builtin_amdgcn_mfma_f32_16x16x32_bf16(vf, pb[0][kp], oacc[0][ni], 0, 0, 0);
          oacc[1][ni] = __builtin_amdgcn_mfma_f32_16x16x32_bf16(vf, pb[1][kp], oacc[1][ni], 0, 0, 0);
        }
      }
    }
    // epilogue: row-sum over the 4 quads (lanes +-16, +-32), write Y bf16
#pragma unroll
    for (int m = 0; m < 2; ++m) {
      float rs = lrow[m];
      rs += __shfl_xor(rs, 16);
      rs += __shfl_xor(rs, 32);
      float inv = 1.0f / rs;
      int qr = wq0 + m * 16 + l15;
      bf16* dst = Y + ((long)(b * SEQ + qr)) * EMB + h * HD + quad * 4;
#pragma unroll
      for (int ni = 0; ni < 4; ++ni) {
        bf16x4 o;
#pragma unroll
        for (int i = 0; i < 4; ++i) o[i] = (bf16)(oacc[m][ni][i] * inv);
        *(bf16x4*)(&dst[ni * 16]) = o;
      }
    }
  }
}

extern "C" void kernel_launch(void* const* d_in, const int* in_sizes, int n_in,
                              void* d_out, int out_size, void* d_ws, size_t ws_size,
                              hipStream_t stream) {
  const float* x      = (const float*)d_in[0];
  const float* W_attn = (const float*)d_in[1];
  const float* b_attn = (const float*)d_in[2];
  const float* W_proj = (const float*)d_in[3];
  const float* b_proj = (const float*)d_in[4];
  float* out = (float*)d_out;
  char* ws = (char*)d_ws;
  bf16* xb  = (bf16*)(ws);                 // 16.78 MB
  bf16* WaT = (bf16*)(ws + 16777216);      //  6.29 MB
  bf16* WpT = (bf16*)(ws + 23068672);      //  2.10 MB
  bf16* Qb  = (bf16*)(ws + 25165824);      // 16.78 MB (pre-scaled)
  bf16* Kb  = (bf16*)(ws + 41943040);      // 16.78 MB
  bf16* Vtb = (bf16*)(ws + 58720256);      // 16.78 MB (transposed [b,h,d,s])
  bf16* Yb  = (bf16*)(ws + 75497472);      // 16.78 MB

  prep<<<12288, 256, 0, stream>>>(x, xb, BATCH * SEQ * EMB,
                                  W_attn, W_proj, WaT, WpT);
  gemm8p<<<768, 256, 0, stream>>>(xb, WaT, b_attn, Qb, Kb, Vtb);
  attn<<<512, 256, 0, stream>>>(Qb, Kb, Vtb, Yb);
  gemm_proj<<<1024, 256, 0, stream>>>(Yb, WpT, b_proj, out);
}